// Round 2
// baseline (1005.282 us; speedup 1.0000x reference)
//
#include <hip/hip_runtime.h>
#include <hip/hip_fp16.h>
#include <stdint.h>

#define B_ROWS 65536
#define K_DIM 3072
#define N_DIM 1024

#define BM 256
#define BN 256
#define BK 64
#define NBLK 4            // N_DIM / BN
#define THREADS 512
#define KSTEPS (K_DIM / BK)   // 48
#define MARGIN 6.0e-3f
#define FB_CAP 8192

typedef _Float16 f16x8 __attribute__((ext_vector_type(8)));
typedef float f32x4 __attribute__((ext_vector_type(4)));

#define BARR() __builtin_amdgcn_s_barrier()
#define VMCNT(n) asm volatile("s_waitcnt vmcnt(" #n ")" ::: "memory")
#define LGKM0() asm volatile("s_waitcnt lgkmcnt(0)" ::: "memory")

__device__ __forceinline__ float gelu_exact(float v) {
  return 0.5f * v * (1.0f + erff(v * 0.7071067811865476f));
}

__device__ __forceinline__ void gld16(const void* g, void* l) {
  __builtin_amdgcn_global_load_lds(
      (const __attribute__((address_space(1))) void*)g,
      (__attribute__((address_space(3))) void*)l, 16, 0, 0);
}

__device__ __forceinline__ f16x8 cvt8(const float4 a, const float4 b) {
  f16x8 h;
  h[0] = (_Float16)a.x; h[1] = (_Float16)a.y; h[2] = (_Float16)a.z; h[3] = (_Float16)a.w;
  h[4] = (_Float16)b.x; h[5] = (_Float16)b.y; h[6] = (_Float16)b.z; h[7] = (_Float16)b.w;
  return h;
}

// ---- kernel 1: build swizzled fp16 B-image of w1 (+ zero fb_cnt) ------------
// Image per (nb, kt): 256 rows (n) x 64 cols (k) fp16, 32KB, laid out exactly
// as the LDS tile: element (row, su*8+j) = w1[kt*64 + (su^(row&7))*8 + j][nb*256+row]
__global__ void k_w1t(const float* __restrict__ w1, _Float16* __restrict__ w1img,
                      int* __restrict__ fb_cnt) {
  if (blockIdx.x == 0 && blockIdx.y == 0 && threadIdx.x == 0) *fb_cnt = 0;
  __shared__ _Float16 lw[64][264];
  const int kt = blockIdx.x, nb = blockIdx.y;
  const int t = threadIdx.x;
  for (int r = 0; r < 64; ++r)
    lw[r][t] = (_Float16)w1[(size_t)(kt * 64 + r) * N_DIM + nb * 256 + t];
  __syncthreads();
  const size_t tbase = ((size_t)(nb * KSTEPS + kt)) << 14;
#pragma unroll
  for (int i = 0; i < 8; ++i) {
    const int U = i * 256 + t;
    const int row = U >> 3, su = U & 7;
    const int u = su ^ (row & 7);
    f16x8 v;
#pragma unroll
    for (int j = 0; j < 8; ++j) v[j] = lw[u * 8 + j][row];
    *(f16x8*)(w1img + tbase + (size_t)U * 8) = v;
  }
}

// ---- kernel 2: 256x256x64 8-phase-style fp16 MFMA GEMM + fused epilogue -----
__global__ __launch_bounds__(THREADS, 2) void k_gemm(
    const float* __restrict__ x, const _Float16* __restrict__ w1img,
    const float* __restrict__ b1, const float* __restrict__ w2,
    float* __restrict__ partial) {
  __shared__ __align__(16) _Float16 Ads[2][BM * BK];   // 2 x 32KB, swizzled
  __shared__ __align__(16) _Float16 Bds[2][BN * BK];   // 2 x 32KB, swizzled

  const int t = threadIdx.x;
  const int lane = t & 63;
  const int wid = t >> 6;
  const int wr = wid >> 2, wc = wid & 3;
  const int l15 = lane & 15, lhi = lane >> 4;
  const int r7 = l15 & 7;

  const int bid = blockIdx.x;
  const int nb = bid & (NBLK - 1);   // n-block fastest -> L3 reuse of x panels
  const int rb = bid >> 2;
  const int row0 = rb * BM;

  // A staging geometry: unit i covers row arow+i*64, k-cols au*8..au*8+7
  const int arow = t >> 3;
  const int au = t & 7;
  const int asu = ((au ^ (arow & 7)) << 3);
  const float* xbase = x + (size_t)(row0 + arow) * K_DIM + au * 8;

  // B staging geometry (4 chunks of 1KB per wave, linear DMA)
  const _Float16* bimg = w1img + ((size_t)(nb * KSTEPS) << 14);
  const int ldsb = wid << 11;   // wave chunk base (elements)

  // fragment read offsets (swizzled)
  const int aoff0 = (wr * 128 + l15) * 64;
  const int boff0 = (wc * 64 + l15) * 64;
  const int su0 = ((lhi) ^ r7) << 3;
  const int su1 = ((4 | lhi) ^ r7) << 3;

  f32x4 acc[8][4];
#pragma unroll
  for (int m = 0; m < 8; ++m)
#pragma unroll
    for (int n = 0; n < 4; ++n) acc[m][n] = (f32x4){0.f, 0.f, 0.f, 0.f};

  _Float16* Acur = Ads[0]; _Float16* Anext = Ads[1];
  _Float16* Bcur = Bds[0]; _Float16* Bnext = Bds[1];
  float4 av[8];
  f16x8 b0[4], b1f[4], afr[4];

#define LD_A(MB, SU)                                                          \
  _Pragma("unroll") for (int m = 0; m < 4; ++m)                               \
      afr[m] = *(const f16x8*)(Acur + aoff0 + ((MB) + m) * 1024 + (SU));
#define LD_B(DST, SU)                                                         \
  _Pragma("unroll") for (int n = 0; n < 4; ++n)                               \
      DST[n] = *(const f16x8*)(Bcur + boff0 + n * 1024 + (SU));
#define MFMA_QUAD(MB, BF)                                                     \
  BARR();                                                                     \
  __builtin_amdgcn_s_setprio(1);                                              \
  _Pragma("unroll") for (int m = 0; m < 4; ++m)                               \
      _Pragma("unroll") for (int n = 0; n < 4; ++n)                           \
          acc[(MB) + m][n] = __builtin_amdgcn_mfma_f32_16x16x32_f16(          \
              afr[m], BF[n], acc[(MB) + m][n], 0, 0, 0);                      \
  __builtin_amdgcn_s_setprio(0);                                              \
  BARR();

  // ---- prologue: stage tile 0 ----
#pragma unroll
  for (int i = 0; i < 4; ++i) {
    const float* p = xbase + (size_t)i * 64 * K_DIM;
    av[2 * i]     = *(const float4*)p;
    av[2 * i + 1] = *(const float4*)(p + 4);
  }
#pragma unroll
  for (int q = 0; q < 4; ++q)
    gld16(bimg + ldsb + q * 512 + lane * 8, Bcur + ldsb + q * 512);
  VMCNT(4);                                  // A loads done (B glds in flight)
#pragma unroll
  for (int i = 0; i < 4; ++i)
    *(f16x8*)(Acur + (arow + i * 64) * 64 + asu) = cvt8(av[2 * i], av[2 * i + 1]);
  VMCNT(0);
  LGKM0();
  BARR();

  // ---- main loop: compute tile kt, stage tile kt+1 ----
  for (int kt = 0; kt < KSTEPS - 1; ++kt) {
    const float* xk = xbase + (kt + 1) * BK;
    const _Float16* bnx = bimg + ((size_t)(kt + 1) << 14);
    // ph0
    av[0] = *(const float4*)(xk);
    av[1] = *(const float4*)(xk + 4);
    av[2] = *(const float4*)(xk + (size_t)64 * K_DIM);
    av[3] = *(const float4*)(xk + (size_t)64 * K_DIM + 4);
    gld16(bnx + ldsb + lane * 8, Bnext + ldsb);
    gld16(bnx + ldsb + 512 + lane * 8, Bnext + ldsb + 512);
    LD_B(b0, su0);
    LD_A(0, su0);
    MFMA_QUAD(0, b0);
    // ph1
    av[4] = *(const float4*)(xk + (size_t)128 * K_DIM);
    av[5] = *(const float4*)(xk + (size_t)128 * K_DIM + 4);
    av[6] = *(const float4*)(xk + (size_t)192 * K_DIM);
    av[7] = *(const float4*)(xk + (size_t)192 * K_DIM + 4);
    gld16(bnx + ldsb + 1024 + lane * 8, Bnext + ldsb + 1024);
    gld16(bnx + ldsb + 1536 + lane * 8, Bnext + ldsb + 1536);
    LD_B(b1f, su1);
    LD_A(0, su1);
    MFMA_QUAD(0, b1f);
    // ph2
    LD_A(4, su0);
    MFMA_QUAD(4, b0);
    // ph3
    LD_A(4, su1);
    VMCNT(2);                 // all 8 A-loads of tile kt+1 complete
#pragma unroll
    for (int i = 0; i < 4; ++i)
      *(f16x8*)(Anext + (arow + i * 64) * 64 + asu) = cvt8(av[2 * i], av[2 * i + 1]);
    VMCNT(0);                 // B glds of tile kt+1 complete (issued ~3 phases ago)
    LGKM0();
    __builtin_amdgcn_sched_barrier(0);
    MFMA_QUAD(4, b1f);
    { _Float16* tp = Acur; Acur = Anext; Anext = tp;
      tp = Bcur; Bcur = Bnext; Bnext = tp; }
  }

  // ---- peeled last tile (compute only) ----
  LD_B(b0, su0);
  LD_A(0, su0);
  MFMA_QUAD(0, b0);
  LD_B(b1f, su1);
  LD_A(0, su1);
  MFMA_QUAD(0, b1f);
  LD_A(4, su0);
  MFMA_QUAD(4, b0);
  LD_A(4, su1);
  MFMA_QUAD(4, b1f);

  // ---- fused epilogue: gelu -> *W2 -> per-row partial logits ----
  __syncthreads();
  float* pl = (float*)&Ads[0][0];   // [256][4][3] overlay
  float w2v[4][3], b1v[4];
  const int n0g = nb * BN;
#pragma unroll
  for (int n = 0; n < 4; ++n) {
    const int gc = n0g + wc * 64 + n * 16 + l15;
    b1v[n] = b1[gc];
    w2v[n][0] = w2[gc * 3 + 0];
    w2v[n][1] = w2[gc * 3 + 1];
    w2v[n][2] = w2[gc * 3 + 2];
  }
#pragma unroll
  for (int m = 0; m < 8; ++m) {
#pragma unroll
    for (int j = 0; j < 4; ++j) {
      float s0 = 0.f, s1 = 0.f, s2 = 0.f;
#pragma unroll
      for (int n = 0; n < 4; ++n) {
        const float g = gelu_exact(acc[m][n][j] + b1v[n]);
        s0 += g * w2v[n][0];
        s1 += g * w2v[n][1];
        s2 += g * w2v[n][2];
      }
#pragma unroll
      for (int off = 1; off < 16; off <<= 1) {
        s0 += __shfl_xor(s0, off, 64);
        s1 += __shfl_xor(s1, off, 64);
        s2 += __shfl_xor(s2, off, 64);
      }
      if (l15 == 0) {
        const int r = wr * 128 + m * 16 + lhi * 4 + j;
        pl[r * 12 + wc * 3 + 0] = s0;
        pl[r * 12 + wc * 3 + 1] = s1;
        pl[r * 12 + wc * 3 + 2] = s2;
      }
    }
  }
  __syncthreads();
  if (t < BM) {
#pragma unroll
    for (int e = 0; e < 3; ++e) {
      partial[(size_t)(row0 + t) * 12 + nb * 3 + e] =
          pl[t * 12 + e] + pl[t * 12 + 3 + e] + pl[t * 12 + 6 + e] + pl[t * 12 + 9 + e];
    }
  }
#undef LD_A
#undef LD_B
#undef MFMA_QUAD
}

// ---- shared finalize: softmax + top-k mask + renorm -------------------------
__device__ __forceinline__ void gate_store(float* __restrict__ out, int r,
                                           float l0, float l1, float l2, int kk) {
  const float mx = fmaxf(l0, fmaxf(l1, l2));
  const float e0 = expf(l0 - mx), e1 = expf(l1 - mx), e2 = expf(l2 - mx);
  const float s = e0 + e1 + e2;
  const float g0 = e0 / s, g1 = e1 / s, g2 = e2 / s;
  const int r0 = (g1 > g0) + (g2 > g0);
  const int r1 = (g0 >= g1) + (g2 > g1);
  const int r2 = (g0 >= g2) + (g1 >= g2);
  const float m0 = (r0 < kk) ? 1.f : 0.f;
  const float m1 = (r1 < kk) ? 1.f : 0.f;
  const float m2 = (r2 < kk) ? 1.f : 0.f;
  const float ks = g0 * m0 + g1 * m1 + g2 * m2;
  const float inv = 1.f / (ks + 1e-8f);
  float* go = out + (size_t)r * 3;
  go[0] = g0 * m0 * inv;
  go[1] = g1 * m1 * inv;
  go[2] = g2 * m2 * inv;
  float* mo = out + (size_t)B_ROWS * 3 + (size_t)r * 3;
  mo[0] = m0;
  mo[1] = m1;
  mo[2] = m2;
}

// ---- kernel 3: logits -> outputs + fallback detect --------------------------
__global__ void k_gate(const float* __restrict__ partial, const float* __restrict__ b2,
                       const int* __restrict__ kp, float* __restrict__ out,
                       int* __restrict__ fb_cnt, int* __restrict__ fb_rows) {
  const int r = blockIdx.x * blockDim.x + threadIdx.x;
  if (r >= B_ROWS) return;
  const float* p = partial + (size_t)r * 12;
  float l0 = b2[0], l1 = b2[1], l2 = b2[2];
#pragma unroll
  for (int c = 0; c < 4; ++c) {
    l0 += p[c * 3 + 0];
    l1 += p[c * 3 + 1];
    l2 += p[c * 3 + 2];
  }
  int kk = *kp;
  kk = kk < 3 ? kk : 3;
  gate_store(out, r, l0, l1, l2, kk);
  const float mx = fmaxf(l0, fmaxf(l1, l2));
  const float mn = fminf(l0, fminf(l1, l2));
  const float mid = l0 + l1 + l2 - mx - mn;
  float gap = 1e30f;
  if (kk == 1) gap = mx - mid;
  else if (kk == 2) gap = mid - mn;
  if (gap < MARGIN) {
    const int i = atomicAdd(fb_cnt, 1);
    if (i < FB_CAP) fb_rows[i] = r;
  }
}

// ---- kernel 4: fp32 exact recompute of near-tie rows (32-row slots) ---------
__global__ __launch_bounds__(256) void k_fb_gemm(
    const float* __restrict__ x, const float* __restrict__ w1,
    const float* __restrict__ b1, const float* __restrict__ w2,
    const int* __restrict__ fb_cnt, const int* __restrict__ fb_rows,
    float* __restrict__ fb_partial) {
  int count = *fb_cnt;
  count = count < FB_CAP ? count : FB_CAP;
  if (count == 0) return;
  const int nc = blockIdx.y, n0 = nc * 64;
  const int t = threadIdx.x, col = t & 63, wrow = t >> 6;
  __shared__ float Xs[32][64];
  __shared__ float Ws[64][64];
  for (int slot = blockIdx.x; slot * 32 < count; slot += gridDim.x) {
    float accr[8] = {0.f, 0.f, 0.f, 0.f, 0.f, 0.f, 0.f, 0.f};
    for (int kt = 0; kt < K_DIM / 64; ++kt) {
      const int k0 = kt * 64;
      __syncthreads();
#pragma unroll
      for (int i = 0; i < 2; ++i) {
        const int idx = i * 256 + t, rr = idx >> 4, c4 = (idx & 15) << 2;
        int gi = slot * 32 + rr;
        gi = gi < count ? gi : count - 1;
        *(float4*)&Xs[rr][c4] = *(const float4*)(x + (size_t)fb_rows[gi] * K_DIM + k0 + c4);
      }
#pragma unroll
      for (int i = 0; i < 4; ++i) {
        const int idx = i * 256 + t, rr = idx >> 4, c4 = (idx & 15) << 2;
        *(float4*)&Ws[rr][c4] = *(const float4*)(w1 + (size_t)(k0 + rr) * N_DIM + n0 + c4);
      }
      __syncthreads();
#pragma unroll 4
      for (int kk = 0; kk < 64; ++kk) {
        const float wv = Ws[kk][col];
#pragma unroll
        for (int rr = 0; rr < 8; ++rr) accr[rr] += Xs[wrow * 8 + rr][kk] * wv;
      }
    }
    const float bv = b1[n0 + col];
    const float w20 = w2[(n0 + col) * 3 + 0];
    const float w21 = w2[(n0 + col) * 3 + 1];
    const float w22 = w2[(n0 + col) * 3 + 2];
#pragma unroll
    for (int rr = 0; rr < 8; ++rr) {
      const float g = gelu_exact(accr[rr] + bv);
      float c0 = g * w20, c1 = g * w21, c2 = g * w22;
#pragma unroll
      for (int off = 1; off < 64; off <<= 1) {
        c0 += __shfl_xor(c0, off, 64);
        c1 += __shfl_xor(c1, off, 64);
        c2 += __shfl_xor(c2, off, 64);
      }
      const int gi = slot * 32 + wrow * 8 + rr;
      if (col == 0 && gi < count) {
        float* fp = fb_partial + ((size_t)gi * 16 + nc) * 3;
        fp[0] = c0;
        fp[1] = c1;
        fp[2] = c2;
      }
    }
  }
}

// ---- kernel 5: finalize fallback rows ---------------------------------------
__global__ void k_fb_fin(const float* __restrict__ fb_partial, const float* __restrict__ b2,
                         const int* __restrict__ kp, const int* __restrict__ fb_cnt,
                         const int* __restrict__ fb_rows, float* __restrict__ out) {
  const int i = blockIdx.x * blockDim.x + threadIdx.x;
  int count = *fb_cnt;
  count = count < FB_CAP ? count : FB_CAP;
  if (i >= count) return;
  const int r = fb_rows[i];
  float l0 = b2[0], l1 = b2[1], l2 = b2[2];
  const float* fp = fb_partial + (size_t)i * 48;
#pragma unroll
  for (int c = 0; c < 16; ++c) {
    l0 += fp[c * 3 + 0];
    l1 += fp[c * 3 + 1];
    l2 += fp[c * 3 + 2];
  }
  int kk = *kp;
  kk = kk < 3 ? kk : 3;
  gate_store(out, r, l0, l1, l2, kk);
}

extern "C" void kernel_launch(void* const* d_in, const int* in_sizes, int n_in,
                              void* d_out, int out_size, void* d_ws, size_t ws_size,
                              hipStream_t stream) {
  (void)in_sizes; (void)n_in; (void)out_size; (void)ws_size;
  const float* x  = (const float*)d_in[0];
  const float* w1 = (const float*)d_in[1];
  const float* b1 = (const float*)d_in[2];
  const float* w2 = (const float*)d_in[3];
  const float* b2 = (const float*)d_in[4];
  const int*   kp = (const int*)d_in[5];
  float* out = (float*)d_out;

  uint8_t* ws = (uint8_t*)d_ws;
  _Float16* w1img   = (_Float16*)(ws);            // 6,291,456 B
  float* partial    = (float*)(ws + 6291456);     // 3,145,728 B
  int* fb_cnt       = (int*)(ws + 9437184);       // 256 B
  int* fb_rows      = (int*)(ws + 9437440);       // 32,768 B
  float* fb_partial = (float*)(ws + 9470208);     // 1,572,864 B (~11 MB total)

  k_w1t<<<dim3(KSTEPS, NBLK), 256, 0, stream>>>(w1, w1img, fb_cnt);
  k_gemm<<<dim3((B_ROWS / BM) * NBLK), THREADS, 0, stream>>>(x, w1img, b1, w2, partial);
  k_gate<<<dim3(B_ROWS / 256), 256, 0, stream>>>(partial, b2, kp, out, fb_cnt, fb_rows);
  k_fb_gemm<<<dim3(16, 16), 256, 0, stream>>>(x, w1, b1, w2, fb_cnt, fb_rows, fb_partial);
  k_fb_fin<<<dim3(FB_CAP / 256), 256, 0, stream>>>(fb_partial, b2, kp, fb_cnt, fb_rows, out);
}

// Round 3
// 953.595 us; speedup vs baseline: 1.0542x; 1.0542x over previous
//
#include <hip/hip_runtime.h>
#include <hip/hip_fp16.h>
#include <stdint.h>

#define B_ROWS 65536
#define K_DIM 3072
#define N_DIM 1024

#define BM 256
#define BN 256
#define BK 64
#define NBLK 4            // N_DIM / BN
#define THREADS 512
#define KSTEPS (K_DIM / BK)   // 48
#define MARGIN 6.0e-3f
#define FB_CAP 8192

typedef _Float16 f16x8 __attribute__((ext_vector_type(8)));
typedef float f32x4 __attribute__((ext_vector_type(4)));

#define BARR() __builtin_amdgcn_s_barrier()
#define VMCNT0() asm volatile("s_waitcnt vmcnt(0)" ::: "memory")
#define LGKM0() asm volatile("s_waitcnt lgkmcnt(0)" ::: "memory")
#define SCHEDB() __builtin_amdgcn_sched_barrier(0)

__device__ __forceinline__ float gelu_exact(float v) {
  return 0.5f * v * (1.0f + erff(v * 0.7071067811865476f));
}

__device__ __forceinline__ void gld16(const void* g, void* l) {
  __builtin_amdgcn_global_load_lds(
      (const __attribute__((address_space(1))) void*)g,
      (__attribute__((address_space(3))) void*)l, 16, 0, 0);
}

__device__ __forceinline__ f16x8 cvt8(const float4 a, const float4 b) {
  f16x8 h;
  h[0] = (_Float16)a.x; h[1] = (_Float16)a.y; h[2] = (_Float16)a.z; h[3] = (_Float16)a.w;
  h[4] = (_Float16)b.x; h[5] = (_Float16)b.y; h[6] = (_Float16)b.z; h[7] = (_Float16)b.w;
  return h;
}

// ---- kernel 1: build swizzled fp16 B-image of w1 (+ zero fb_cnt) ------------
// Image per (nb, kt): 256 rows (n) x 64 cols (k) fp16, 32KB, laid out exactly
// as the LDS tile: element (row, su*8+j) = w1[kt*64 + (su^(row&7))*8 + j][nb*256+row]
__global__ void k_w1t(const float* __restrict__ w1, _Float16* __restrict__ w1img,
                      int* __restrict__ fb_cnt) {
  if (blockIdx.x == 0 && blockIdx.y == 0 && threadIdx.x == 0) *fb_cnt = 0;
  __shared__ _Float16 lw[64][264];
  const int kt = blockIdx.x, nb = blockIdx.y;
  const int t = threadIdx.x;
  for (int r = 0; r < 64; ++r)
    lw[r][t] = (_Float16)w1[(size_t)(kt * 64 + r) * N_DIM + nb * 256 + t];
  __syncthreads();
  const size_t tbase = ((size_t)(nb * KSTEPS + kt)) << 14;
#pragma unroll
  for (int i = 0; i < 8; ++i) {
    const int U = i * 256 + t;
    const int row = U >> 3, su = U & 7;
    const int u = su ^ (row & 7);
    f16x8 v;
#pragma unroll
    for (int j = 0; j < 8; ++j) v[j] = lw[u * 8 + j][row];
    *(f16x8*)(w1img + tbase + (size_t)U * 8) = v;
  }
}

// ---- kernel 2: 256x256x64 deep-pipelined fp16 MFMA GEMM + fused epilogue ----
__global__ __launch_bounds__(THREADS, 2) void k_gemm(
    const float* __restrict__ x, const _Float16* __restrict__ w1img,
    const float* __restrict__ b1, const float* __restrict__ w2,
    float* __restrict__ partial) {
  __shared__ __align__(16) _Float16 Ads[2][BM * BK];   // 2 x 32KB, swizzled
  __shared__ __align__(16) _Float16 Bds[2][BN * BK];   // 2 x 32KB, swizzled

  const int t = threadIdx.x;
  const int lane = t & 63;
  const int wid = t >> 6;
  const int wr = wid >> 2, wc = wid & 3;
  const int l15 = lane & 15, lhi = lane >> 4;
  const int r7 = l15 & 7;

  const int bid = blockIdx.x;
  const int nb = bid & (NBLK - 1);   // n-block fastest -> L3 reuse of x panels
  const int rb = bid >> 2;
  const int row0 = rb * BM;

  // A staging geometry: thread covers rows arow + {0,64,128,192}, k-cols au*8..+7
  const int arow = t >> 3;
  const int au = t & 7;
  const int asu = ((au ^ (arow & 7)) << 3);
  const float* xbase = x + (size_t)(row0 + arow) * K_DIM + au * 8;

  // B staging geometry (4 chunks of 1KB per wave, linear DMA, pre-swizzled src)
  const _Float16* bimg = w1img + ((size_t)(nb * KSTEPS) << 14);
  const int ldsb = wid << 11;   // wave chunk base (elements)

  // fragment read offsets (swizzled)
  const int aoff0 = (wr * 128 + l15) * 64;
  const int boff0 = (wc * 64 + l15) * 64;
  const int su0 = ((lhi) ^ r7) << 3;
  const int su1 = ((4 | lhi) ^ r7) << 3;

  f32x4 acc[8][4];
#pragma unroll
  for (int m = 0; m < 8; ++m)
#pragma unroll
    for (int n = 0; n < 4; ++n) acc[m][n] = (f32x4){0.f, 0.f, 0.f, 0.f};

  _Float16* Acur = Ads[0]; _Float16* Anext = Ads[1];
  _Float16* Bcur = Bds[0]; _Float16* Bnext = Bds[1];
  float4 av[8];
  f16x8 b0[4], b1f[4], afr[4];

#define LD_A(MB, SU)                                                          \
  _Pragma("unroll") for (int m = 0; m < 4; ++m)                               \
      afr[m] = *(const f16x8*)(Acur + aoff0 + ((MB) + m) * 1024 + (SU));
#define LD_B(DST, SU)                                                         \
  _Pragma("unroll") for (int n = 0; n < 4; ++n)                               \
      DST[n] = *(const f16x8*)(Bcur + boff0 + n * 1024 + (SU));
#define MFMA16(MB, BF)                                                        \
  __builtin_amdgcn_s_setprio(1);                                              \
  _Pragma("unroll") for (int m = 0; m < 4; ++m)                               \
      _Pragma("unroll") for (int n = 0; n < 4; ++n)                           \
          acc[(MB) + m][n] = __builtin_amdgcn_mfma_f32_16x16x32_f16(          \
              afr[m], BF[n], acc[(MB) + m][n], 0, 0, 0);                      \
  __builtin_amdgcn_s_setprio(0);
#define ISSUE_A(XK)                                                           \
  av[0] = *(const float4*)(XK);                                               \
  av[1] = *(const float4*)((XK) + 4);                                         \
  av[2] = *(const float4*)((XK) + (size_t)64 * K_DIM);                        \
  av[3] = *(const float4*)((XK) + (size_t)64 * K_DIM + 4);                    \
  av[4] = *(const float4*)((XK) + (size_t)128 * K_DIM);                       \
  av[5] = *(const float4*)((XK) + (size_t)128 * K_DIM + 4);                   \
  av[6] = *(const float4*)((XK) + (size_t)192 * K_DIM);                       \
  av[7] = *(const float4*)((XK) + (size_t)192 * K_DIM + 4);
#define ISSUE_B(BNX, DST)                                                     \
  gld16((BNX) + ldsb + lane * 8, (DST) + ldsb);                               \
  gld16((BNX) + ldsb + 512 + lane * 8, (DST) + ldsb + 512);                   \
  gld16((BNX) + ldsb + 1024 + lane * 8, (DST) + ldsb + 1024);                 \
  gld16((BNX) + ldsb + 1536 + lane * 8, (DST) + ldsb + 1536);
#define WRITE_A(DST)                                                          \
  _Pragma("unroll") for (int i = 0; i < 4; ++i)                               \
      *(f16x8*)((DST) + (arow + i * 64) * 64 + asu) = cvt8(av[2 * i], av[2 * i + 1]);

  // ---- prologue: stage tile 0 (A first, then B -> FIFO lets A-wait leave B) ----
  ISSUE_A(xbase);
  SCHEDB();
  ISSUE_B(bimg, Bcur);
  SCHEDB();
  WRITE_A(Acur);      // compiler inserts exact vmcnt for av (leaves B in flight)
  VMCNT0();           // B(0) glds done
  LGKM0();
  BARR();

  // ---- main loop: compute tile kt, stage tile kt+1 (issued at TOP) ----
  for (int kt = 0; kt < KSTEPS - 1; ++kt) {
    const float* xk = xbase + (kt + 1) * BK;
    const _Float16* bnx = bimg + ((size_t)(kt + 1) << 14);
    ISSUE_A(xk);            // 8 float4 -> regs, waited ~3/4 tile later
    SCHEDB();
    ISSUE_B(bnx, Bnext);    // 4 glds -> LDS DMA, waited a full tile later
    SCHEDB();
    // quad 0
    LD_B(b0, su0);
    LD_A(0, su0);
    BARR();
    MFMA16(0, b0);
    BARR();
    // quad 1
    LD_B(b1f, su1);
    LD_A(0, su1);
    BARR();
    MFMA16(0, b1f);
    BARR();
    // quad 2
    LD_A(4, su0);
    BARR();
    MFMA16(4, b0);
    BARR();
    // stage-write A(kt+1): compiler auto vmcnt(4) (A done, B still in flight)
    WRITE_A(Anext);
    // quad 3
    LD_A(4, su1);
    BARR();
    MFMA16(4, b1f);
    VMCNT0();               // B(kt+1): issued a full tile ago -> hot drain
    LGKM0();                // A ds_writes + frag reads drained
    BARR();                 // tile boundary: everyone's staging visible
    { _Float16* tp = Acur; Acur = Anext; Anext = tp;
      tp = Bcur; Bcur = Bnext; Bnext = tp; }
  }

  // ---- peeled last tile (compute only) ----
  LD_B(b0, su0);
  LD_A(0, su0);
  BARR();
  MFMA16(0, b0);
  BARR();
  LD_B(b1f, su1);
  LD_A(0, su1);
  BARR();
  MFMA16(0, b1f);
  BARR();
  LD_A(4, su0);
  BARR();
  MFMA16(4, b0);
  BARR();
  LD_A(4, su1);
  BARR();
  MFMA16(4, b1f);

  // ---- fused epilogue: gelu -> *W2 -> per-row partial logits ----
  __syncthreads();
  float* pl = (float*)&Ads[0][0];   // [256][4][3] overlay
  float w2v[4][3], b1v[4];
  const int n0g = nb * BN;
#pragma unroll
  for (int n = 0; n < 4; ++n) {
    const int gc = n0g + wc * 64 + n * 16 + l15;
    b1v[n] = b1[gc];
    w2v[n][0] = w2[gc * 3 + 0];
    w2v[n][1] = w2[gc * 3 + 1];
    w2v[n][2] = w2[gc * 3 + 2];
  }
#pragma unroll
  for (int m = 0; m < 8; ++m) {
#pragma unroll
    for (int j = 0; j < 4; ++j) {
      float s0 = 0.f, s1 = 0.f, s2 = 0.f;
#pragma unroll
      for (int n = 0; n < 4; ++n) {
        const float g = gelu_exact(acc[m][n][j] + b1v[n]);
        s0 += g * w2v[n][0];
        s1 += g * w2v[n][1];
        s2 += g * w2v[n][2];
      }
#pragma unroll
      for (int off = 1; off < 16; off <<= 1) {
        s0 += __shfl_xor(s0, off, 64);
        s1 += __shfl_xor(s1, off, 64);
        s2 += __shfl_xor(s2, off, 64);
      }
      if (l15 == 0) {
        const int r = wr * 128 + m * 16 + lhi * 4 + j;
        pl[r * 12 + wc * 3 + 0] = s0;
        pl[r * 12 + wc * 3 + 1] = s1;
        pl[r * 12 + wc * 3 + 2] = s2;
      }
    }
  }
  __syncthreads();
  if (t < BM) {
#pragma unroll
    for (int e = 0; e < 3; ++e) {
      partial[(size_t)(row0 + t) * 12 + nb * 3 + e] =
          pl[t * 12 + e] + pl[t * 12 + 3 + e] + pl[t * 12 + 6 + e] + pl[t * 12 + 9 + e];
    }
  }
#undef LD_A
#undef LD_B
#undef MFMA16
#undef ISSUE_A
#undef ISSUE_B
#undef WRITE_A
}

// ---- shared finalize: softmax + top-k mask + renorm -------------------------
__device__ __forceinline__ void gate_store(float* __restrict__ out, int r,
                                           float l0, float l1, float l2, int kk) {
  const float mx = fmaxf(l0, fmaxf(l1, l2));
  const float e0 = expf(l0 - mx), e1 = expf(l1 - mx), e2 = expf(l2 - mx);
  const float s = e0 + e1 + e2;
  const float g0 = e0 / s, g1 = e1 / s, g2 = e2 / s;
  const int r0 = (g1 > g0) + (g2 > g0);
  const int r1 = (g0 >= g1) + (g2 > g1);
  const int r2 = (g0 >= g2) + (g1 >= g2);
  const float m0 = (r0 < kk) ? 1.f : 0.f;
  const float m1 = (r1 < kk) ? 1.f : 0.f;
  const float m2 = (r2 < kk) ? 1.f : 0.f;
  const float ks = g0 * m0 + g1 * m1 + g2 * m2;
  const float inv = 1.f / (ks + 1e-8f);
  float* go = out + (size_t)r * 3;
  go[0] = g0 * m0 * inv;
  go[1] = g1 * m1 * inv;
  go[2] = g2 * m2 * inv;
  float* mo = out + (size_t)B_ROWS * 3 + (size_t)r * 3;
  mo[0] = m0;
  mo[1] = m1;
  mo[2] = m2;
}

// ---- kernel 3: logits -> outputs + fallback detect --------------------------
__global__ void k_gate(const float* __restrict__ partial, const float* __restrict__ b2,
                       const int* __restrict__ kp, float* __restrict__ out,
                       int* __restrict__ fb_cnt, int* __restrict__ fb_rows) {
  const int r = blockIdx.x * blockDim.x + threadIdx.x;
  if (r >= B_ROWS) return;
  const float* p = partial + (size_t)r * 12;
  float l0 = b2[0], l1 = b2[1], l2 = b2[2];
#pragma unroll
  for (int c = 0; c < 4; ++c) {
    l0 += p[c * 3 + 0];
    l1 += p[c * 3 + 1];
    l2 += p[c * 3 + 2];
  }
  int kk = *kp;
  kk = kk < 3 ? kk : 3;
  gate_store(out, r, l0, l1, l2, kk);
  const float mx = fmaxf(l0, fmaxf(l1, l2));
  const float mn = fminf(l0, fminf(l1, l2));
  const float mid = l0 + l1 + l2 - mx - mn;
  float gap = 1e30f;
  if (kk == 1) gap = mx - mid;
  else if (kk == 2) gap = mid - mn;
  if (gap < MARGIN) {
    const int i = atomicAdd(fb_cnt, 1);
    if (i < FB_CAP) fb_rows[i] = r;
  }
}

// ---- kernel 4: fp32 exact recompute of near-tie rows (32-row slots) ---------
__global__ __launch_bounds__(256) void k_fb_gemm(
    const float* __restrict__ x, const float* __restrict__ w1,
    const float* __restrict__ b1, const float* __restrict__ w2,
    const int* __restrict__ fb_cnt, const int* __restrict__ fb_rows,
    float* __restrict__ fb_partial) {
  int count = *fb_cnt;
  count = count < FB_CAP ? count : FB_CAP;
  if (count == 0) return;
  const int nc = blockIdx.y, n0 = nc * 64;
  const int t = threadIdx.x, col = t & 63, wrow = t >> 6;
  __shared__ float Xs[32][64];
  __shared__ float Ws[64][64];
  for (int slot = blockIdx.x; slot * 32 < count; slot += gridDim.x) {
    float accr[8] = {0.f, 0.f, 0.f, 0.f, 0.f, 0.f, 0.f, 0.f};
    for (int kt = 0; kt < K_DIM / 64; ++kt) {
      const int k0 = kt * 64;
      __syncthreads();
#pragma unroll
      for (int i = 0; i < 2; ++i) {
        const int idx = i * 256 + t, rr = idx >> 4, c4 = (idx & 15) << 2;
        int gi = slot * 32 + rr;
        gi = gi < count ? gi : count - 1;
        *(float4*)&Xs[rr][c4] = *(const float4*)(x + (size_t)fb_rows[gi] * K_DIM + k0 + c4);
      }
#pragma unroll
      for (int i = 0; i < 4; ++i) {
        const int idx = i * 256 + t, rr = idx >> 4, c4 = (idx & 15) << 2;
        *(float4*)&Ws[rr][c4] = *(const float4*)(w1 + (size_t)(k0 + rr) * N_DIM + n0 + c4);
      }
      __syncthreads();
#pragma unroll 4
      for (int kk = 0; kk < 64; ++kk) {
        const float wv = Ws[kk][col];
#pragma unroll
        for (int rr = 0; rr < 8; ++rr) accr[rr] += Xs[wrow * 8 + rr][kk] * wv;
      }
    }
    const float bv = b1[n0 + col];
    const float w20 = w2[(n0 + col) * 3 + 0];
    const float w21 = w2[(n0 + col) * 3 + 1];
    const float w22 = w2[(n0 + col) * 3 + 2];
#pragma unroll
    for (int rr = 0; rr < 8; ++rr) {
      const float g = gelu_exact(accr[rr] + bv);
      float c0 = g * w20, c1 = g * w21, c2 = g * w22;
#pragma unroll
      for (int off = 1; off < 64; off <<= 1) {
        c0 += __shfl_xor(c0, off, 64);
        c1 += __shfl_xor(c1, off, 64);
        c2 += __shfl_xor(c2, off, 64);
      }
      const int gi = slot * 32 + wrow * 8 + rr;
      if (col == 0 && gi < count) {
        float* fp = fb_partial + ((size_t)gi * 16 + nc) * 3;
        fp[0] = c0;
        fp[1] = c1;
        fp[2] = c2;
      }
    }
  }
}

// ---- kernel 5: finalize fallback rows ---------------------------------------
__global__ void k_fb_fin(const float* __restrict__ fb_partial, const float* __restrict__ b2,
                         const int* __restrict__ kp, const int* __restrict__ fb_cnt,
                         const int* __restrict__ fb_rows, float* __restrict__ out) {
  const int i = blockIdx.x * blockDim.x + threadIdx.x;
  int count = *fb_cnt;
  count = count < FB_CAP ? count : FB_CAP;
  if (i >= count) return;
  const int r = fb_rows[i];
  float l0 = b2[0], l1 = b2[1], l2 = b2[2];
  const float* fp = fb_partial + (size_t)i * 48;
#pragma unroll
  for (int c = 0; c < 16; ++c) {
    l0 += fp[c * 3 + 0];
    l1 += fp[c * 3 + 1];
    l2 += fp[c * 3 + 2];
  }
  int kk = *kp;
  kk = kk < 3 ? kk : 3;
  gate_store(out, r, l0, l1, l2, kk);
}

extern "C" void kernel_launch(void* const* d_in, const int* in_sizes, int n_in,
                              void* d_out, int out_size, void* d_ws, size_t ws_size,
                              hipStream_t stream) {
  (void)in_sizes; (void)n_in; (void)out_size; (void)ws_size;
  const float* x  = (const float*)d_in[0];
  const float* w1 = (const float*)d_in[1];
  const float* b1 = (const float*)d_in[2];
  const float* w2 = (const float*)d_in[3];
  const float* b2 = (const float*)d_in[4];
  const int*   kp = (const int*)d_in[5];
  float* out = (float*)d_out;

  uint8_t* ws = (uint8_t*)d_ws;
  _Float16* w1img   = (_Float16*)(ws);            // 6,291,456 B
  float* partial    = (float*)(ws + 6291456);     // 3,145,728 B
  int* fb_cnt       = (int*)(ws + 9437184);       // 256 B
  int* fb_rows      = (int*)(ws + 9437440);       // 32,768 B
  float* fb_partial = (float*)(ws + 9470208);     // 1,572,864 B (~11 MB total)

  k_w1t<<<dim3(KSTEPS, NBLK), 256, 0, stream>>>(w1, w1img, fb_cnt);
  k_gemm<<<dim3((B_ROWS / BM) * NBLK), THREADS, 0, stream>>>(x, w1img, b1, w2, partial);
  k_gate<<<dim3(B_ROWS / 256), 256, 0, stream>>>(partial, b2, kp, out, fb_cnt, fb_rows);
  k_fb_gemm<<<dim3(16, 16), 256, 0, stream>>>(x, w1, b1, w2, fb_cnt, fb_rows, fb_partial);
  k_fb_fin<<<dim3(FB_CAP / 256), 256, 0, stream>>>(fb_partial, b2, kp, fb_cnt, fb_rows, out);
}

// Round 4
// 795.311 us; speedup vs baseline: 1.2640x; 1.1990x over previous
//
#include <hip/hip_runtime.h>
#include <hip/hip_fp16.h>
#include <stdint.h>

#define B_ROWS 65536
#define K_DIM 3072
#define N_DIM 1024

#define BM 128
#define BN 256
#define BK 64
#define NBLK 4            // N_DIM / BN
#define THREADS 512
#define KSTEPS (K_DIM / BK)   // 48
#define MARGIN 6.0e-3f
#define FB_CAP 8192

typedef _Float16 f16x8 __attribute__((ext_vector_type(8)));
typedef float f32x4 __attribute__((ext_vector_type(4)));

#define VMCNT0() asm volatile("s_waitcnt vmcnt(0)" ::: "memory")
#define LGKM0() asm volatile("s_waitcnt lgkmcnt(0)" ::: "memory")
#define SCHEDB() __builtin_amdgcn_sched_barrier(0)

__device__ __forceinline__ float gelu_exact(float v) {
  return 0.5f * v * (1.0f + erff(v * 0.7071067811865476f));
}

__device__ __forceinline__ void gld16(const void* g, void* l) {
  __builtin_amdgcn_global_load_lds(
      (const __attribute__((address_space(1))) void*)g,
      (__attribute__((address_space(3))) void*)l, 16, 0, 0);
}

__device__ __forceinline__ f16x8 cvt8(const float4 a, const float4 b) {
  f16x8 h;
  h[0] = (_Float16)a.x; h[1] = (_Float16)a.y; h[2] = (_Float16)a.z; h[3] = (_Float16)a.w;
  h[4] = (_Float16)b.x; h[5] = (_Float16)b.y; h[6] = (_Float16)b.z; h[7] = (_Float16)b.w;
  return h;
}

// ---- kernel 1: build swizzled fp16 B-image of w1 (+ zero fb_cnt) ------------
// Image per (nb, kt): 256 rows (n) x 64 cols (k) fp16, 32KB, laid out exactly
// as the LDS tile: element (row, su*8+j) = w1[kt*64 + (su^(row&7))*8 + j][nb*256+row]
__global__ void k_w1t(const float* __restrict__ w1, _Float16* __restrict__ w1img,
                      int* __restrict__ fb_cnt) {
  if (blockIdx.x == 0 && blockIdx.y == 0 && threadIdx.x == 0) *fb_cnt = 0;
  __shared__ _Float16 lw[64][264];
  const int kt = blockIdx.x, nb = blockIdx.y;
  const int t = threadIdx.x;
  for (int r = 0; r < 64; ++r)
    lw[r][t] = (_Float16)w1[(size_t)(kt * 64 + r) * N_DIM + nb * 256 + t];
  __syncthreads();
  const size_t tbase = ((size_t)(nb * KSTEPS + kt)) << 14;
#pragma unroll
  for (int i = 0; i < 8; ++i) {
    const int U = i * 256 + t;
    const int row = U >> 3, su = U & 7;
    const int u = su ^ (row & 7);
    f16x8 v;
#pragma unroll
    for (int j = 0; j < 8; ++j) v[j] = lw[u * 8 + j][row];
    *(f16x8*)(w1img + tbase + (size_t)U * 8) = v;
  }
}

// ---- kernel 2: 128x256x64 fp16 MFMA GEMM, B-DMA dbuf, fused epilogue --------
__global__ __launch_bounds__(THREADS, 4) void k_gemm(
    const float* __restrict__ x, const _Float16* __restrict__ w1img,
    const float* __restrict__ b1, const float* __restrict__ w2,
    float* __restrict__ partial) {
  __shared__ __align__(16) _Float16 As[BM * BK];       // 16 KB, swizzled fp16
  __shared__ __align__(16) _Float16 Bds[2][BN * BK];   // 2 x 32 KB, swizzled

  const int t = threadIdx.x;
  const int lane = t & 63;
  const int wid = t >> 6;
  const int wr = wid >> 2, wc = wid & 3;       // 2 x 4 wave grid
  const int l15 = lane & 15, lhi = lane >> 4;
  const int r7 = l15 & 7;

  // XCD-chunked swizzle: the 4 nb-blocks of one rb land on the same XCD,
  // dispatched adjacently -> x panel served from that XCD's L2.
  const int bid = blockIdx.x;
  const int swz = (bid & 7) * ((B_ROWS / BM) * NBLK / 8) + (bid >> 3);
  const int nb = swz & (NBLK - 1);
  const int rb = swz >> 2;
  const int row0 = rb * BM;

  // A staging geometry: thread -> (row = t>>2, q = t&3), 16 f32 = 2 swizzled slots
  const int arow = t >> 2;
  const int aq = t & 3;
  const int as0 = ((2 * aq) ^ (arow & 7)) << 3;        // f16 elem offset of slot
  const int as1 = ((2 * aq + 1) ^ (arow & 7)) << 3;
  const float* xbase = x + (size_t)(row0 + arow) * K_DIM + aq * 16;

  // B staging geometry (4 x 1KB chunks per wave, linear DMA, pre-swizzled src)
  const _Float16* bimg = w1img + ((size_t)(nb * KSTEPS) << 14);
  const int ldsb = wid << 11;   // wave chunk base (elements)

  // fragment read offsets (swizzled, same scheme for A and B)
  const int aoff0 = (wr * 64 + l15) * 64;
  const int boff0 = (wc * 64 + l15) * 64;
  const int su0 = (lhi ^ r7) << 3;            // kk = 0
  const int su1 = ((4 + lhi) ^ r7) << 3;      // kk = 32

  f32x4 acc[4][4];
#pragma unroll
  for (int m = 0; m < 4; ++m)
#pragma unroll
    for (int n = 0; n < 4; ++n) acc[m][n] = (f32x4){0.f, 0.f, 0.f, 0.f};

#define ISSUE_B(BNX, DST)                                                     \
  gld16((BNX) + ldsb + lane * 8, (DST) + ldsb);                               \
  gld16((BNX) + ldsb + 512 + lane * 8, (DST) + ldsb + 512);                   \
  gld16((BNX) + ldsb + 1024 + lane * 8, (DST) + ldsb + 1024);                 \
  gld16((BNX) + ldsb + 1536 + lane * 8, (DST) + ldsb + 1536);
#define STAGE_A(K0)                                                           \
  {                                                                           \
    const float* xp = xbase + (K0);                                           \
    float4 a0 = *(const float4*)(xp);                                         \
    float4 a1 = *(const float4*)(xp + 4);                                     \
    float4 a2 = *(const float4*)(xp + 8);                                     \
    float4 a3 = *(const float4*)(xp + 12);                                    \
    *(f16x8*)(As + arow * 64 + as0) = cvt8(a0, a1);                           \
    *(f16x8*)(As + arow * 64 + as1) = cvt8(a2, a3);                           \
  }
#define COMPUTE(BCUR)                                                         \
  {                                                                           \
    f16x8 af[4], bf[4];                                                       \
    _Pragma("unroll") for (int m = 0; m < 4; ++m)                             \
        af[m] = *(const f16x8*)(As + aoff0 + m * 1024 + su0);                 \
    _Pragma("unroll") for (int n = 0; n < 4; ++n)                             \
        bf[n] = *(const f16x8*)((BCUR) + boff0 + n * 1024 + su0);             \
    _Pragma("unroll") for (int m = 0; m < 4; ++m)                             \
        _Pragma("unroll") for (int n = 0; n < 4; ++n)                         \
            acc[m][n] = __builtin_amdgcn_mfma_f32_16x16x32_f16(               \
                af[m], bf[n], acc[m][n], 0, 0, 0);                            \
    _Pragma("unroll") for (int m = 0; m < 4; ++m)                             \
        af[m] = *(const f16x8*)(As + aoff0 + m * 1024 + su1);                 \
    _Pragma("unroll") for (int n = 0; n < 4; ++n)                             \
        bf[n] = *(const f16x8*)((BCUR) + boff0 + n * 1024 + su1);             \
    _Pragma("unroll") for (int m = 0; m < 4; ++m)                             \
        _Pragma("unroll") for (int n = 0; n < 4; ++n)                         \
            acc[m][n] = __builtin_amdgcn_mfma_f32_16x16x32_f16(               \
                af[m], bf[n], acc[m][n], 0, 0, 0);                            \
  }

  // ---- prologue: stage tile 0 (A regs first, then B DMA) ----
  STAGE_A(0);
  ISSUE_B(bimg, Bds[0]);
  VMCNT0();
  LGKM0();
  __syncthreads();

  // ---- main loop: 2 barriers per tile, B-DMA prefetched a full compute ahead
  int buf = 0;
  for (int kt = 0; kt < KSTEPS; ++kt) {
    if (kt < KSTEPS - 1) {
      const _Float16* bnx = bimg + ((size_t)(kt + 1) << 14);
      ISSUE_B(bnx, Bds[buf ^ 1]);     // DMA next B while computing current
      SCHEDB();
    }
    COMPUTE(Bds[buf]);
    __syncthreads();                  // As + Bds[buf] fully consumed
    if (kt < KSTEPS - 1) {
      STAGE_A((kt + 1) * BK);         // overwrite As for next tile
      VMCNT0();                       // B DMA (issued pre-compute) done
      LGKM0();
    }
    __syncthreads();
    buf ^= 1;
  }

  // ---- fused epilogue: gelu -> *W2 -> per-row partial logits ----
  float* pl = (float*)&As[0];   // [128][4][3] overlay (6 KB < 16 KB)
  float w2v[4][3], b1v[4];
  const int n0g = nb * BN;
#pragma unroll
  for (int n = 0; n < 4; ++n) {
    const int gc = n0g + wc * 64 + n * 16 + l15;
    b1v[n] = b1[gc];
    w2v[n][0] = w2[gc * 3 + 0];
    w2v[n][1] = w2[gc * 3 + 1];
    w2v[n][2] = w2[gc * 3 + 2];
  }
#pragma unroll
  for (int m = 0; m < 4; ++m) {
#pragma unroll
    for (int j = 0; j < 4; ++j) {
      float s0 = 0.f, s1 = 0.f, s2 = 0.f;
#pragma unroll
      for (int n = 0; n < 4; ++n) {
        const float g = gelu_exact(acc[m][n][j] + b1v[n]);
        s0 += g * w2v[n][0];
        s1 += g * w2v[n][1];
        s2 += g * w2v[n][2];
      }
#pragma unroll
      for (int off = 1; off < 16; off <<= 1) {
        s0 += __shfl_xor(s0, off, 64);
        s1 += __shfl_xor(s1, off, 64);
        s2 += __shfl_xor(s2, off, 64);
      }
      if (l15 == 0) {
        const int r = wr * 64 + m * 16 + lhi * 4 + j;
        pl[r * 12 + wc * 3 + 0] = s0;
        pl[r * 12 + wc * 3 + 1] = s1;
        pl[r * 12 + wc * 3 + 2] = s2;
      }
    }
  }
  __syncthreads();
  if (t < BM) {
#pragma unroll
    for (int e = 0; e < 3; ++e) {
      partial[(size_t)(row0 + t) * 12 + nb * 3 + e] =
          pl[t * 12 + e] + pl[t * 12 + 3 + e] + pl[t * 12 + 6 + e] + pl[t * 12 + 9 + e];
    }
  }
#undef ISSUE_B
#undef STAGE_A
#undef COMPUTE
}

// ---- shared finalize: softmax + top-k mask + renorm -------------------------
__device__ __forceinline__ void gate_store(float* __restrict__ out, int r,
                                           float l0, float l1, float l2, int kk) {
  const float mx = fmaxf(l0, fmaxf(l1, l2));
  const float e0 = expf(l0 - mx), e1 = expf(l1 - mx), e2 = expf(l2 - mx);
  const float s = e0 + e1 + e2;
  const float g0 = e0 / s, g1 = e1 / s, g2 = e2 / s;
  const int r0 = (g1 > g0) + (g2 > g0);
  const int r1 = (g0 >= g1) + (g2 > g1);
  const int r2 = (g0 >= g2) + (g1 >= g2);
  const float m0 = (r0 < kk) ? 1.f : 0.f;
  const float m1 = (r1 < kk) ? 1.f : 0.f;
  const float m2 = (r2 < kk) ? 1.f : 0.f;
  const float ks = g0 * m0 + g1 * m1 + g2 * m2;
  const float inv = 1.f / (ks + 1e-8f);
  float* go = out + (size_t)r * 3;
  go[0] = g0 * m0 * inv;
  go[1] = g1 * m1 * inv;
  go[2] = g2 * m2 * inv;
  float* mo = out + (size_t)B_ROWS * 3 + (size_t)r * 3;
  mo[0] = m0;
  mo[1] = m1;
  mo[2] = m2;
}

// ---- kernel 3: logits -> outputs + fallback detect --------------------------
__global__ void k_gate(const float* __restrict__ partial, const float* __restrict__ b2,
                       const int* __restrict__ kp, float* __restrict__ out,
                       int* __restrict__ fb_cnt, int* __restrict__ fb_rows) {
  const int r = blockIdx.x * blockDim.x + threadIdx.x;
  if (r >= B_ROWS) return;
  const float* p = partial + (size_t)r * 12;
  float l0 = b2[0], l1 = b2[1], l2 = b2[2];
#pragma unroll
  for (int c = 0; c < 4; ++c) {
    l0 += p[c * 3 + 0];
    l1 += p[c * 3 + 1];
    l2 += p[c * 3 + 2];
  }
  int kk = *kp;
  kk = kk < 3 ? kk : 3;
  gate_store(out, r, l0, l1, l2, kk);
  const float mx = fmaxf(l0, fmaxf(l1, l2));
  const float mn = fminf(l0, fminf(l1, l2));
  const float mid = l0 + l1 + l2 - mx - mn;
  float gap = 1e30f;
  if (kk == 1) gap = mx - mid;
  else if (kk == 2) gap = mid - mn;
  if (gap < MARGIN) {
    const int i = atomicAdd(fb_cnt, 1);
    if (i < FB_CAP) fb_rows[i] = r;
  }
}

// ---- kernel 4: fp32 exact recompute of near-tie rows (32-row slots) ---------
__global__ __launch_bounds__(256) void k_fb_gemm(
    const float* __restrict__ x, const float* __restrict__ w1,
    const float* __restrict__ b1, const float* __restrict__ w2,
    const int* __restrict__ fb_cnt, const int* __restrict__ fb_rows,
    float* __restrict__ fb_partial) {
  int count = *fb_cnt;
  count = count < FB_CAP ? count : FB_CAP;
  if (count == 0) return;
  const int nc = blockIdx.y, n0 = nc * 64;
  const int t = threadIdx.x, col = t & 63, wrow = t >> 6;
  __shared__ float Xs[32][64];
  __shared__ float Ws[64][64];
  for (int slot = blockIdx.x; slot * 32 < count; slot += gridDim.x) {
    float accr[8] = {0.f, 0.f, 0.f, 0.f, 0.f, 0.f, 0.f, 0.f};
    for (int kt = 0; kt < K_DIM / 64; ++kt) {
      const int k0 = kt * 64;
      __syncthreads();
#pragma unroll
      for (int i = 0; i < 2; ++i) {
        const int idx = i * 256 + t, rr = idx >> 4, c4 = (idx & 15) << 2;
        int gi = slot * 32 + rr;
        gi = gi < count ? gi : count - 1;
        *(float4*)&Xs[rr][c4] = *(const float4*)(x + (size_t)fb_rows[gi] * K_DIM + k0 + c4);
      }
#pragma unroll
      for (int i = 0; i < 4; ++i) {
        const int idx = i * 256 + t, rr = idx >> 4, c4 = (idx & 15) << 2;
        *(float4*)&Ws[rr][c4] = *(const float4*)(w1 + (size_t)(k0 + rr) * N_DIM + n0 + c4);
      }
      __syncthreads();
#pragma unroll 4
      for (int kk = 0; kk < 64; ++kk) {
        const float wv = Ws[kk][col];
#pragma unroll
        for (int rr = 0; rr < 8; ++rr) accr[rr] += Xs[wrow * 8 + rr][kk] * wv;
      }
    }
    const float bv = b1[n0 + col];
    const float w20 = w2[(n0 + col) * 3 + 0];
    const float w21 = w2[(n0 + col) * 3 + 1];
    const float w22 = w2[(n0 + col) * 3 + 2];
#pragma unroll
    for (int rr = 0; rr < 8; ++rr) {
      const float g = gelu_exact(accr[rr] + bv);
      float c0 = g * w20, c1 = g * w21, c2 = g * w22;
#pragma unroll
      for (int off = 1; off < 64; off <<= 1) {
        c0 += __shfl_xor(c0, off, 64);
        c1 += __shfl_xor(c1, off, 64);
        c2 += __shfl_xor(c2, off, 64);
      }
      const int gi = slot * 32 + wrow * 8 + rr;
      if (col == 0 && gi < count) {
        float* fp = fb_partial + ((size_t)gi * 16 + nc) * 3;
        fp[0] = c0;
        fp[1] = c1;
        fp[2] = c2;
      }
    }
  }
}

// ---- kernel 5: finalize fallback rows ---------------------------------------
__global__ void k_fb_fin(const float* __restrict__ fb_partial, const float* __restrict__ b2,
                         const int* __restrict__ kp, const int* __restrict__ fb_cnt,
                         const int* __restrict__ fb_rows, float* __restrict__ out) {
  const int i = blockIdx.x * blockDim.x + threadIdx.x;
  int count = *fb_cnt;
  count = count < FB_CAP ? count : FB_CAP;
  if (i >= count) return;
  const int r = fb_rows[i];
  float l0 = b2[0], l1 = b2[1], l2 = b2[2];
  const float* fp = fb_partial + (size_t)i * 48;
#pragma unroll
  for (int c = 0; c < 16; ++c) {
    l0 += fp[c * 3 + 0];
    l1 += fp[c * 3 + 1];
    l2 += fp[c * 3 + 2];
  }
  int kk = *kp;
  kk = kk < 3 ? kk : 3;
  gate_store(out, r, l0, l1, l2, kk);
}

extern "C" void kernel_launch(void* const* d_in, const int* in_sizes, int n_in,
                              void* d_out, int out_size, void* d_ws, size_t ws_size,
                              hipStream_t stream) {
  (void)in_sizes; (void)n_in; (void)out_size; (void)ws_size;
  const float* x  = (const float*)d_in[0];
  const float* w1 = (const float*)d_in[1];
  const float* b1 = (const float*)d_in[2];
  const float* w2 = (const float*)d_in[3];
  const float* b2 = (const float*)d_in[4];
  const int*   kp = (const int*)d_in[5];
  float* out = (float*)d_out;

  uint8_t* ws = (uint8_t*)d_ws;
  _Float16* w1img   = (_Float16*)(ws);            // 6,291,456 B
  float* partial    = (float*)(ws + 6291456);     // 3,145,728 B
  int* fb_cnt       = (int*)(ws + 9437184);       // 256 B
  int* fb_rows      = (int*)(ws + 9437440);       // 32,768 B
  float* fb_partial = (float*)(ws + 9470208);     // 1,572,864 B (~11 MB total)

  k_w1t<<<dim3(KSTEPS, NBLK), 256, 0, stream>>>(w1, w1img, fb_cnt);
  k_gemm<<<dim3((B_ROWS / BM) * NBLK), THREADS, 0, stream>>>(x, w1img, b1, w2, partial);
  k_gate<<<dim3(B_ROWS / 256), 256, 0, stream>>>(partial, b2, kp, out, fb_cnt, fb_rows);
  k_fb_gemm<<<dim3(16, 16), 256, 0, stream>>>(x, w1, b1, w2, fb_cnt, fb_rows, fb_partial);
  k_fb_fin<<<dim3(FB_CAP / 256), 256, 0, stream>>>(fb_partial, b2, kp, fb_cnt, fb_rows, out);
}

// Round 5
// 744.492 us; speedup vs baseline: 1.3503x; 1.0683x over previous
//
#include <hip/hip_runtime.h>
#include <hip/hip_fp16.h>
#include <stdint.h>

#define B_ROWS 65536
#define K_DIM 3072
#define N_DIM 1024

#define BM 128
#define BN 256
#define BK 64
#define NBLK 4            // N_DIM / BN
#define THREADS 512
#define KSTEPS (K_DIM / BK)   // 48
#define MARGIN 6.0e-3f
#define FB_CAP 8192

typedef _Float16 f16x8 __attribute__((ext_vector_type(8)));
typedef float f32x4 __attribute__((ext_vector_type(4)));

#define VMCNT0() asm volatile("s_waitcnt vmcnt(0)" ::: "memory")
#define LGKM0() asm volatile("s_waitcnt lgkmcnt(0)" ::: "memory")
#define SCHEDB() __builtin_amdgcn_sched_barrier(0)

__device__ __forceinline__ float gelu_exact(float v) {
  return 0.5f * v * (1.0f + erff(v * 0.7071067811865476f));
}

__device__ __forceinline__ void gld16(const void* g, void* l) {
  __builtin_amdgcn_global_load_lds(
      (const __attribute__((address_space(1))) void*)g,
      (__attribute__((address_space(3))) void*)l, 16, 0, 0);
}

__device__ __forceinline__ f16x8 cvt8(const float4 a, const float4 b) {
  f16x8 h;
  h[0] = (_Float16)a.x; h[1] = (_Float16)a.y; h[2] = (_Float16)a.z; h[3] = (_Float16)a.w;
  h[4] = (_Float16)b.x; h[5] = (_Float16)b.y; h[6] = (_Float16)b.z; h[7] = (_Float16)b.w;
  return h;
}

// ---- kernel 1: build swizzled fp16 B-image of w1 (+ zero fb_cnt) ------------
// Image per (nb, kt): 256 rows (n) x 64 cols (k) fp16, 32KB, laid out exactly
// as the LDS tile: element (row, su*8+j) = w1[kt*64 + (su^(row&7))*8 + j][nb*256+row]
__global__ void k_w1t(const float* __restrict__ w1, _Float16* __restrict__ w1img,
                      int* __restrict__ fb_cnt) {
  if (blockIdx.x == 0 && blockIdx.y == 0 && threadIdx.x == 0) *fb_cnt = 0;
  __shared__ _Float16 lw[64][264];
  const int kt = blockIdx.x, nb = blockIdx.y;
  const int t = threadIdx.x;
  for (int r = 0; r < 64; ++r)
    lw[r][t] = (_Float16)w1[(size_t)(kt * 64 + r) * N_DIM + nb * 256 + t];
  __syncthreads();
  const size_t tbase = ((size_t)(nb * KSTEPS + kt)) << 14;
#pragma unroll
  for (int i = 0; i < 8; ++i) {
    const int U = i * 256 + t;
    const int row = U >> 3, su = U & 7;
    const int u = su ^ (row & 7);
    f16x8 v;
#pragma unroll
    for (int j = 0; j < 8; ++j) v[j] = lw[u * 8 + j][row];
    *(f16x8*)(w1img + tbase + (size_t)U * 8) = v;
  }
}

// ---- kernel 2: 128x256x64 fp16 MFMA GEMM, B-DMA dbuf, A issue-early ---------
__global__ __launch_bounds__(THREADS, 4) void k_gemm(
    const float* __restrict__ x, const _Float16* __restrict__ w1img,
    const float* __restrict__ b1, const float* __restrict__ w2,
    float* __restrict__ partial) {
  __shared__ __align__(16) _Float16 As[BM * BK];       // 16 KB, swizzled fp16
  __shared__ __align__(16) _Float16 Bds[2][BN * BK];   // 2 x 32 KB, swizzled

  const int t = threadIdx.x;
  const int lane = t & 63;
  const int wid = t >> 6;
  const int wr = wid >> 2, wc = wid & 3;       // 2 x 4 wave grid
  const int l15 = lane & 15, lhi = lane >> 4;
  const int r7 = l15 & 7;

  // XCD-chunked swizzle: the 4 nb-blocks of one rb land on the same XCD,
  // dispatched adjacently -> x panel served from that XCD's L2.
  const int bid = blockIdx.x;
  const int swz = (bid & 7) * ((B_ROWS / BM) * NBLK / 8) + (bid >> 3);
  const int nb = swz & (NBLK - 1);
  const int rb = swz >> 2;
  const int row0 = rb * BM;

  // A staging geometry: thread -> (row = t>>2, q = t&3), 16 f32 = 2 swizzled slots
  const int arow = t >> 2;
  const int aq = t & 3;
  const int as0 = ((2 * aq) ^ (arow & 7)) << 3;        // f16 elem offset of slot
  const int as1 = ((2 * aq + 1) ^ (arow & 7)) << 3;
  const float* xbase = x + (size_t)(row0 + arow) * K_DIM + aq * 16;

  // B staging geometry (4 x 1KB chunks per wave, linear DMA, pre-swizzled src)
  const _Float16* bimg = w1img + ((size_t)(nb * KSTEPS) << 14);
  const int ldsb = wid << 11;   // wave chunk base (elements)

  // fragment read offsets (swizzled, same scheme for A and B)
  const int aoff0 = (wr * 64 + l15) * 64;
  const int boff0 = (wc * 64 + l15) * 64;
  const int su0 = (lhi ^ r7) << 3;            // kk = 0
  const int su1 = ((4 + lhi) ^ r7) << 3;      // kk = 32

  f32x4 acc[4][4];
#pragma unroll
  for (int m = 0; m < 4; ++m)
#pragma unroll
    for (int n = 0; n < 4; ++n) acc[m][n] = (f32x4){0.f, 0.f, 0.f, 0.f};

  float4 av[4];   // in-flight A registers (issued early, written late)

#define ISSUE_B(BNX, DST)                                                     \
  gld16((BNX) + ldsb + lane * 8, (DST) + ldsb);                               \
  gld16((BNX) + ldsb + 512 + lane * 8, (DST) + ldsb + 512);                   \
  gld16((BNX) + ldsb + 1024 + lane * 8, (DST) + ldsb + 1024);                 \
  gld16((BNX) + ldsb + 1536 + lane * 8, (DST) + ldsb + 1536);
#define ISSUE_A(K0)                                                           \
  {                                                                           \
    const float* xp = xbase + (K0);                                           \
    av[0] = *(const float4*)(xp);                                             \
    av[1] = *(const float4*)(xp + 4);                                         \
    av[2] = *(const float4*)(xp + 8);                                         \
    av[3] = *(const float4*)(xp + 12);                                        \
  }
#define WRITE_A()                                                             \
  *(f16x8*)(As + arow * 64 + as0) = cvt8(av[0], av[1]);                       \
  *(f16x8*)(As + arow * 64 + as1) = cvt8(av[2], av[3]);
#define COMPUTE(BCUR)                                                         \
  {                                                                           \
    f16x8 af[4], bf[4];                                                       \
    _Pragma("unroll") for (int m = 0; m < 4; ++m)                             \
        af[m] = *(const f16x8*)(As + aoff0 + m * 1024 + su0);                 \
    _Pragma("unroll") for (int n = 0; n < 4; ++n)                             \
        bf[n] = *(const f16x8*)((BCUR) + boff0 + n * 1024 + su0);             \
    __builtin_amdgcn_s_setprio(1);                                            \
    _Pragma("unroll") for (int m = 0; m < 4; ++m)                             \
        _Pragma("unroll") for (int n = 0; n < 4; ++n)                         \
            acc[m][n] = __builtin_amdgcn_mfma_f32_16x16x32_f16(               \
                af[m], bf[n], acc[m][n], 0, 0, 0);                            \
    __builtin_amdgcn_s_setprio(0);                                            \
    _Pragma("unroll") for (int m = 0; m < 4; ++m)                             \
        af[m] = *(const f16x8*)(As + aoff0 + m * 1024 + su1);                 \
    _Pragma("unroll") for (int n = 0; n < 4; ++n)                             \
        bf[n] = *(const f16x8*)((BCUR) + boff0 + n * 1024 + su1);             \
    __builtin_amdgcn_s_setprio(1);                                            \
    _Pragma("unroll") for (int m = 0; m < 4; ++m)                             \
        _Pragma("unroll") for (int n = 0; n < 4; ++n)                         \
            acc[m][n] = __builtin_amdgcn_mfma_f32_16x16x32_f16(               \
                af[m], bf[n], acc[m][n], 0, 0, 0);                            \
    __builtin_amdgcn_s_setprio(0);                                            \
  }

  // ---- prologue: stage tile 0 (A regs first, then B DMA; FIFO order) ----
  ISSUE_A(0);
  SCHEDB();
  ISSUE_B(bimg, Bds[0]);
  SCHEDB();
  WRITE_A();          // compiler inserts vmcnt(4): av done, B DMA still in flight
  VMCNT0();
  LGKM0();
  __syncthreads();

  // ---- main loop: A issued early (T14 split), B DMA a full compute ahead ----
  int buf = 0;
  for (int kt = 0; kt < KSTEPS; ++kt) {
    if (kt < KSTEPS - 1) {
      ISSUE_A((kt + 1) * BK);         // 4 float4 in flight across COMPUTE
      SCHEDB();
      const _Float16* bnx = bimg + ((size_t)(kt + 1) << 14);
      ISSUE_B(bnx, Bds[buf ^ 1]);     // DMA next B while computing current
      SCHEDB();
    }
    COMPUTE(Bds[buf]);
    __syncthreads();                  // As + Bds[buf] fully consumed
    if (kt < KSTEPS - 1) {
      WRITE_A();                      // vmcnt(4) hot: av arrived during COMPUTE
      VMCNT0();                       // B DMA (issued pre-compute) done
      LGKM0();
    }
    __syncthreads();
    buf ^= 1;
  }

  // ---- fused epilogue: gelu -> *W2 -> per-row partial logits ----
  float* pl = (float*)&As[0];   // [128][4][3] overlay (6 KB < 16 KB)
  float w2v[4][3], b1v[4];
  const int n0g = nb * BN;
#pragma unroll
  for (int n = 0; n < 4; ++n) {
    const int gc = n0g + wc * 64 + n * 16 + l15;
    b1v[n] = b1[gc];
    w2v[n][0] = w2[gc * 3 + 0];
    w2v[n][1] = w2[gc * 3 + 1];
    w2v[n][2] = w2[gc * 3 + 2];
  }
#pragma unroll
  for (int m = 0; m < 4; ++m) {
#pragma unroll
    for (int j = 0; j < 4; ++j) {
      float s0 = 0.f, s1 = 0.f, s2 = 0.f;
#pragma unroll
      for (int n = 0; n < 4; ++n) {
        const float g = gelu_exact(acc[m][n][j] + b1v[n]);
        s0 += g * w2v[n][0];
        s1 += g * w2v[n][1];
        s2 += g * w2v[n][2];
      }
#pragma unroll
      for (int off = 1; off < 16; off <<= 1) {
        s0 += __shfl_xor(s0, off, 64);
        s1 += __shfl_xor(s1, off, 64);
        s2 += __shfl_xor(s2, off, 64);
      }
      if (l15 == 0) {
        const int r = wr * 64 + m * 16 + lhi * 4 + j;
        pl[r * 12 + wc * 3 + 0] = s0;
        pl[r * 12 + wc * 3 + 1] = s1;
        pl[r * 12 + wc * 3 + 2] = s2;
      }
    }
  }
  __syncthreads();
  if (t < BM) {
#pragma unroll
    for (int e = 0; e < 3; ++e) {
      partial[(size_t)(row0 + t) * 12 + nb * 3 + e] =
          pl[t * 12 + e] + pl[t * 12 + 3 + e] + pl[t * 12 + 6 + e] + pl[t * 12 + 9 + e];
    }
  }
#undef ISSUE_B
#undef ISSUE_A
#undef WRITE_A
#undef COMPUTE
}

// ---- shared finalize: softmax + top-k mask + renorm -------------------------
__device__ __forceinline__ void gate_store(float* __restrict__ out, int r,
                                           float l0, float l1, float l2, int kk) {
  const float mx = fmaxf(l0, fmaxf(l1, l2));
  const float e0 = expf(l0 - mx), e1 = expf(l1 - mx), e2 = expf(l2 - mx);
  const float s = e0 + e1 + e2;
  const float g0 = e0 / s, g1 = e1 / s, g2 = e2 / s;
  const int r0 = (g1 > g0) + (g2 > g0);
  const int r1 = (g0 >= g1) + (g2 > g1);
  const int r2 = (g0 >= g2) + (g1 >= g2);
  const float m0 = (r0 < kk) ? 1.f : 0.f;
  const float m1 = (r1 < kk) ? 1.f : 0.f;
  const float m2 = (r2 < kk) ? 1.f : 0.f;
  const float ks = g0 * m0 + g1 * m1 + g2 * m2;
  const float inv = 1.f / (ks + 1e-8f);
  float* go = out + (size_t)r * 3;
  go[0] = g0 * m0 * inv;
  go[1] = g1 * m1 * inv;
  go[2] = g2 * m2 * inv;
  float* mo = out + (size_t)B_ROWS * 3 + (size_t)r * 3;
  mo[0] = m0;
  mo[1] = m1;
  mo[2] = m2;
}

// ---- kernel 3: logits -> outputs + fallback detect --------------------------
__global__ void k_gate(const float* __restrict__ partial, const float* __restrict__ b2,
                       const int* __restrict__ kp, float* __restrict__ out,
                       int* __restrict__ fb_cnt, int* __restrict__ fb_rows) {
  const int r = blockIdx.x * blockDim.x + threadIdx.x;
  if (r >= B_ROWS) return;
  const float* p = partial + (size_t)r * 12;
  float l0 = b2[0], l1 = b2[1], l2 = b2[2];
#pragma unroll
  for (int c = 0; c < 4; ++c) {
    l0 += p[c * 3 + 0];
    l1 += p[c * 3 + 1];
    l2 += p[c * 3 + 2];
  }
  int kk = *kp;
  kk = kk < 3 ? kk : 3;
  gate_store(out, r, l0, l1, l2, kk);
  const float mx = fmaxf(l0, fmaxf(l1, l2));
  const float mn = fminf(l0, fminf(l1, l2));
  const float mid = l0 + l1 + l2 - mx - mn;
  float gap = 1e30f;
  if (kk == 1) gap = mx - mid;
  else if (kk == 2) gap = mid - mn;
  if (gap < MARGIN) {
    const int i = atomicAdd(fb_cnt, 1);
    if (i < FB_CAP) fb_rows[i] = r;
  }
}

// ---- kernel 4: fp32 exact recompute of near-tie rows (32-row slots) ---------
__global__ __launch_bounds__(256) void k_fb_gemm(
    const float* __restrict__ x, const float* __restrict__ w1,
    const float* __restrict__ b1, const float* __restrict__ w2,
    const int* __restrict__ fb_cnt, const int* __restrict__ fb_rows,
    float* __restrict__ fb_partial) {
  int count = *fb_cnt;
  count = count < FB_CAP ? count : FB_CAP;
  if (count == 0) return;
  const int nc = blockIdx.y, n0 = nc * 64;
  const int t = threadIdx.x, col = t & 63, wrow = t >> 6;
  __shared__ float Xs[32][64];
  __shared__ float Ws[64][64];
  for (int slot = blockIdx.x; slot * 32 < count; slot += gridDim.x) {
    float accr[8] = {0.f, 0.f, 0.f, 0.f, 0.f, 0.f, 0.f, 0.f};
    for (int kt = 0; kt < K_DIM / 64; ++kt) {
      const int k0 = kt * 64;
      __syncthreads();
#pragma unroll
      for (int i = 0; i < 2; ++i) {
        const int idx = i * 256 + t, rr = idx >> 4, c4 = (idx & 15) << 2;
        int gi = slot * 32 + rr;
        gi = gi < count ? gi : count - 1;
        *(float4*)&Xs[rr][c4] = *(const float4*)(x + (size_t)fb_rows[gi] * K_DIM + k0 + c4);
      }
#pragma unroll
      for (int i = 0; i < 4; ++i) {
        const int idx = i * 256 + t, rr = idx >> 4, c4 = (idx & 15) << 2;
        *(float4*)&Ws[rr][c4] = *(const float4*)(w1 + (size_t)(k0 + rr) * N_DIM + n0 + c4);
      }
      __syncthreads();
#pragma unroll 4
      for (int kk = 0; kk < 64; ++kk) {
        const float wv = Ws[kk][col];
#pragma unroll
        for (int rr = 0; rr < 8; ++rr) accr[rr] += Xs[wrow * 8 + rr][kk] * wv;
      }
    }
    const float bv = b1[n0 + col];
    const float w20 = w2[(n0 + col) * 3 + 0];
    const float w21 = w2[(n0 + col) * 3 + 1];
    const float w22 = w2[(n0 + col) * 3 + 2];
#pragma unroll
    for (int rr = 0; rr < 8; ++rr) {
      const float g = gelu_exact(accr[rr] + bv);
      float c0 = g * w20, c1 = g * w21, c2 = g * w22;
#pragma unroll
      for (int off = 1; off < 64; off <<= 1) {
        c0 += __shfl_xor(c0, off, 64);
        c1 += __shfl_xor(c1, off, 64);
        c2 += __shfl_xor(c2, off, 64);
      }
      const int gi = slot * 32 + wrow * 8 + rr;
      if (col == 0 && gi < count) {
        float* fp = fb_partial + ((size_t)gi * 16 + nc) * 3;
        fp[0] = c0;
        fp[1] = c1;
        fp[2] = c2;
      }
    }
  }
}

// ---- kernel 5: finalize fallback rows ---------------------------------------
__global__ void k_fb_fin(const float* __restrict__ fb_partial, const float* __restrict__ b2,
                         const int* __restrict__ kp, const int* __restrict__ fb_cnt,
                         const int* __restrict__ fb_rows, float* __restrict__ out) {
  const int i = blockIdx.x * blockDim.x + threadIdx.x;
  int count = *fb_cnt;
  count = count < FB_CAP ? count : FB_CAP;
  if (i >= count) return;
  const int r = fb_rows[i];
  float l0 = b2[0], l1 = b2[1], l2 = b2[2];
  const float* fp = fb_partial + (size_t)i * 48;
#pragma unroll
  for (int c = 0; c < 16; ++c) {
    l0 += fp[c * 3 + 0];
    l1 += fp[c * 3 + 1];
    l2 += fp[c * 3 + 2];
  }
  int kk = *kp;
  kk = kk < 3 ? kk : 3;
  gate_store(out, r, l0, l1, l2, kk);
}

extern "C" void kernel_launch(void* const* d_in, const int* in_sizes, int n_in,
                              void* d_out, int out_size, void* d_ws, size_t ws_size,
                              hipStream_t stream) {
  (void)in_sizes; (void)n_in; (void)out_size; (void)ws_size;
  const float* x  = (const float*)d_in[0];
  const float* w1 = (const float*)d_in[1];
  const float* b1 = (const float*)d_in[2];
  const float* w2 = (const float*)d_in[3];
  const float* b2 = (const float*)d_in[4];
  const int*   kp = (const int*)d_in[5];
  float* out = (float*)d_out;

  uint8_t* ws = (uint8_t*)d_ws;
  _Float16* w1img   = (_Float16*)(ws);            // 6,291,456 B
  float* partial    = (float*)(ws + 6291456);     // 3,145,728 B
  int* fb_cnt       = (int*)(ws + 9437184);       // 256 B
  int* fb_rows      = (int*)(ws + 9437440);       // 32,768 B
  float* fb_partial = (float*)(ws + 9470208);     // 1,572,864 B (~11 MB total)

  k_w1t<<<dim3(KSTEPS, NBLK), 256, 0, stream>>>(w1, w1img, fb_cnt);
  k_gemm<<<dim3((B_ROWS / BM) * NBLK), THREADS, 0, stream>>>(x, w1img, b1, w2, partial);
  k_gate<<<dim3(B_ROWS / 256), 256, 0, stream>>>(partial, b2, kp, out, fb_cnt, fb_rows);
  k_fb_gemm<<<dim3(16, 16), 256, 0, stream>>>(x, w1, b1, w2, fb_cnt, fb_rows, fb_partial);
  k_fb_fin<<<dim3(FB_CAP / 256), 256, 0, stream>>>(fb_partial, b2, kp, fb_cnt, fb_rows, out);
}